// Round 1
// baseline (2281.639 us; speedup 1.0000x reference)
//
#include <hip/hip_runtime.h>

#define NR 8192
#define DIN 768
#define DH 16384
#define KTOP 32
#define CAND 160

typedef __attribute__((ext_vector_type(8))) __bf16 bf16x8;
typedef __attribute__((ext_vector_type(4))) __bf16 bf16x4;
typedef __attribute__((ext_vector_type(4))) float f32x4;

__device__ __forceinline__ void gload16(const void* g, void* s) {
  __builtin_amdgcn_global_load_lds((const __attribute__((address_space(1))) void*)g,
                                   (__attribute__((address_space(3))) void*)s, 16, 0, 0);
}

// f32 -> (hi, lo) bf16 split, 4 elems/thread
__global__ __launch_bounds__(256) void k_split(const float* __restrict__ in,
    __bf16* __restrict__ hi, __bf16* __restrict__ lo, int n4) {
  int i = blockIdx.x * 256 + threadIdx.x;
  if (i >= n4) return;
  float4 v = ((const float4*)in)[i];
  bf16x4 h, l;
  float f;
  f = v.x; h[0] = (__bf16)f; l[0] = (__bf16)(f - (float)h[0]);
  f = v.y; h[1] = (__bf16)f; l[1] = (__bf16)(f - (float)h[1]);
  f = v.z; h[2] = (__bf16)f; l[2] = (__bf16)(f - (float)h[2]);
  f = v.w; h[3] = (__bf16)f; l[3] = (__bf16)(f - (float)h[3]);
  ((bf16x4*)hi)[i] = h;
  ((bf16x4*)lo)[i] = l;
}

// W_dec [768][16384] -> wdecT [16384][768]
__global__ __launch_bounds__(256) void k_transpose(const float* __restrict__ in,
                                                   float* __restrict__ outT) {
  __shared__ float tile[32][33];
  int tx = threadIdx.x, ty = threadIdx.y;
  int hb = blockIdx.x * 32, db = blockIdx.y * 32;
  for (int i = 0; i < 32; i += 8)
    tile[ty + i][tx] = in[(size_t)(db + ty + i) * DH + hb + tx];
  __syncthreads();
  for (int i = 0; i < 32; i += 8)
    outT[(size_t)(hb + ty + i) * DIN + db + tx] = tile[tx][ty + i];
}

// split-bf16 GEMM: out[NR][DH] = relu(x @ W_enc^T), 3-term hi/lo compensation
__global__ __launch_bounds__(256) void k_gemm(const __bf16* __restrict__ Ah,
    const __bf16* __restrict__ Al, const __bf16* __restrict__ Bh,
    const __bf16* __restrict__ Bl, float* __restrict__ out) {
  __shared__ __bf16 sAh[128 * 64], sAl[128 * 64], sBh[128 * 64], sBl[128 * 64];
  const int tid = threadIdx.x;
  const int l = tid & 63;
  const int w = tid >> 6;
  const int wm = w >> 1, wn = w & 1;
  const size_t row0 = (size_t)blockIdx.y * 128;
  const size_t col0 = (size_t)blockIdx.x * 128;
  f32x4 acc[4][4] = {};
  const int cr = l >> 3;         // row within 8-row chunk
  const int cc = (l & 7) * 8;    // k-element offset
  for (int t = 0; t < 12; ++t) {
    const int k0 = t * 64;
    for (int i = 0; i < 4; ++i) {
      const int c = i * 4 + w;       // chunk 0..15 (wave-uniform)
      const int r = c * 8 + cr;      // tile row 0..127
      const int ldso = c * 512;      // LDS element offset (1KB chunks)
      gload16(Ah + (row0 + r) * DIN + k0 + cc, sAh + ldso);
      gload16(Al + (row0 + r) * DIN + k0 + cc, sAl + ldso);
      gload16(Bh + (col0 + r) * DIN + k0 + cc, sBh + ldso);
      gload16(Bl + (col0 + r) * DIN + k0 + cc, sBl + ldso);
    }
    __syncthreads();
#pragma unroll
    for (int kk = 0; kk < 2; ++kk) {
      const int kb = kk * 32 + (l >> 4) * 8;
      bf16x8 ah[4], al[4], bh[4], bl[4];
#pragma unroll
      for (int mi = 0; mi < 4; ++mi) {
        int ro = (wm * 64 + mi * 16 + (l & 15)) * 64 + kb;
        ah[mi] = *(const bf16x8*)(sAh + ro);
        al[mi] = *(const bf16x8*)(sAl + ro);
      }
#pragma unroll
      for (int ni = 0; ni < 4; ++ni) {
        int ro = (wn * 64 + ni * 16 + (l & 15)) * 64 + kb;
        bh[ni] = *(const bf16x8*)(sBh + ro);
        bl[ni] = *(const bf16x8*)(sBl + ro);
      }
#pragma unroll
      for (int mi = 0; mi < 4; ++mi)
#pragma unroll
        for (int ni = 0; ni < 4; ++ni) {
          acc[mi][ni] = __builtin_amdgcn_mfma_f32_16x16x32_bf16(ah[mi], bh[ni], acc[mi][ni], 0, 0, 0);
          acc[mi][ni] = __builtin_amdgcn_mfma_f32_16x16x32_bf16(ah[mi], bl[ni], acc[mi][ni], 0, 0, 0);
          acc[mi][ni] = __builtin_amdgcn_mfma_f32_16x16x32_bf16(al[mi], bh[ni], acc[mi][ni], 0, 0, 0);
        }
    }
    __syncthreads();
  }
#pragma unroll
  for (int mi = 0; mi < 4; ++mi)
#pragma unroll
    for (int ni = 0; ni < 4; ++ni)
#pragma unroll
      for (int rg = 0; rg < 4; ++rg) {
        size_t rr = row0 + wm * 64 + mi * 16 + (l >> 4) * 4 + rg;
        size_t cg = col0 + wn * 64 + ni * 16 + (l & 15);
        float v = acc[mi][ni][rg];
        out[rr * DH + cg] = v > 0.f ? v : 0.f;
      }
}

// per-row exact top-32 (radix cutoff + rank sort), f64 tie refinement,
// in-place zero+scatter of the latent row, emit (idx,val) lists.
__global__ __launch_bounds__(256) void k_topk(float* __restrict__ lat,
    const float* __restrict__ x, const float* __restrict__ W_enc,
    float* __restrict__ fvals, int* __restrict__ fidx) {
  const int r = blockIdx.x;
  const int tid = threadIdx.x;
  float* row = lat + (size_t)r * DH;
  __shared__ float sval[DH];
  __shared__ int hist[256];
  __shared__ int suf[256];
  __shared__ float cval[CAND];
  __shared__ int cidx[CAND];
  __shared__ float sv[CAND];
  __shared__ int sidx[CAND];
  __shared__ double dval[CAND];
  __shared__ int s_cnt, s_b, s_na, s_s;

  float4* sval4 = (float4*)sval;
  const float4* row4 = (const float4*)row;
  for (int i = tid; i < DH / 4; i += 256) sval4[i] = row4[i];
  hist[tid] = 0;
  __syncthreads();
  // pass 1: histogram of top byte (values >= 0 post-relu; uint order == float order)
  for (int i = tid; i < DH; i += 256) {
    unsigned u = __float_as_uint(sval[i]);
    if (u) atomicAdd(&hist[u >> 24], 1);
  }
  __syncthreads();
  { int s = 0; for (int j = tid; j < 256; ++j) s += hist[j]; suf[tid] = s; }
  __syncthreads();
  if (tid == 0) {
    int b = 255;
    while (b > 0 && suf[b] < KTOP) --b;
    s_b = b;
    s_na = (b < 255) ? suf[b + 1] : 0;
  }
  __syncthreads();
  const int bstar = s_b, na = s_na;
  hist[tid] = 0;
  __syncthreads();
  // pass 2: second byte within boundary bin
  for (int i = tid; i < DH; i += 256) {
    unsigned u = __float_as_uint(sval[i]);
    if (u && (u >> 24) == (unsigned)bstar) atomicAdd(&hist[(u >> 16) & 255], 1);
  }
  __syncthreads();
  { int s = 0; for (int j = tid; j < 256; ++j) s += hist[j]; suf[tid] = s; }
  __syncthreads();
  if (tid == 0) {
    int s = 255;
    while (s > 0 && na + suf[s] < KTOP) --s;
    s_s = s;
    s_cnt = 0;
  }
  __syncthreads();
  unsigned U = ((unsigned)bstar << 24) | ((unsigned)s_s << 16);
  unsigned Ug = (U >= (1u << 16)) ? U - (1u << 16) : 0u;  // one sub-bin lower: margin guard
  for (int i = tid; i < DH; i += 256) {
    unsigned u = __float_as_uint(sval[i]);
    if (u && u >= Ug) {
      int p = atomicAdd(&s_cnt, 1);
      if (p < CAND) { cval[p] = sval[i]; cidx[p] = i; }
    }
  }
  __syncthreads();
  const int C = min(s_cnt, CAND);
  if (tid < C) {
    float v = cval[tid];
    int rk = 0;
    for (int j = 0; j < C; ++j) {
      float vj = cval[j];
      rk += (vj > v) || (vj == v && j < tid);
    }
    sv[rk] = v; sidx[rk] = cidx[tid];
  }
  __syncthreads();
  bool amb = (C > KTOP) && (sv[KTOP - 1] - sv[KTOP] < 1e-4f);
  if (amb) {
    // f64 recompute of all candidates: selection becomes f64-exact
    const int wl = tid & 63, wv = tid >> 6;
    const float* xr = x + (size_t)r * DIN;
    for (int c = wv; c < C; c += 4) {
      const float* wrow = W_enc + (size_t)cidx[c] * DIN;
      double s = 0.0;
      for (int k = wl; k < DIN; k += 64)
        s += (double)xr[k] * (double)wrow[k];
#pragma unroll
      for (int off = 32; off; off >>= 1) s += __shfl_down(s, off);
      if (wl == 0) dval[c] = s > 0.0 ? s : 0.0;
    }
    __syncthreads();
    if (tid < C) {
      double v = dval[tid];
      int rk = 0;
      for (int j = 0; j < C; ++j) {
        double vj = dval[j];
        rk += (vj > v) || (vj == v && j < tid);
      }
      sv[rk] = (float)v; sidx[rk] = cidx[tid];
    }
    __syncthreads();
  }
  // zero the row in place, then scatter the kept 32
  float4 z = {0.f, 0.f, 0.f, 0.f};
  for (int i = tid; i < DH / 4; i += 256) ((float4*)row)[i] = z;
  __syncthreads();
  if (tid < KTOP && tid < C) {
    row[sidx[tid]] = sv[tid];
    fvals[r * KTOP + tid] = sv[tid];
    fidx[r * KTOP + tid] = sidx[tid];
  }
}

// recon[r][:] = sum_j val_j * wdecT[idx_j][:]
__global__ __launch_bounds__(256) void k_decode(const float* __restrict__ fvals,
    const int* __restrict__ fidx, const float* __restrict__ wdecT,
    float* __restrict__ recon) {
  const int r = blockIdx.x, tid = threadIdx.x;
  __shared__ float lv[KTOP];
  __shared__ int li[KTOP];
  if (tid < KTOP) { lv[tid] = fvals[r * KTOP + tid]; li[tid] = fidx[r * KTOP + tid]; }
  __syncthreads();
  float a0 = 0.f, a1 = 0.f, a2 = 0.f;
#pragma unroll
  for (int j = 0; j < KTOP; ++j) {
    const float* wrow = wdecT + (size_t)li[j] * DIN;
    float v = lv[j];
    a0 += v * wrow[tid];
    a1 += v * wrow[tid + 256];
    a2 += v * wrow[tid + 512];
  }
  float* o = recon + (size_t)r * DIN;
  o[tid] = a0;
  o[tid + 256] = a1;
  o[tid + 512] = a2;
}

extern "C" void kernel_launch(void* const* d_in, const int* in_sizes, int n_in,
                              void* d_out, int out_size, void* d_ws, size_t ws_size,
                              hipStream_t stream) {
  const float* x = (const float*)d_in[0];
  const float* W_enc = (const float*)d_in[1];
  const float* W_dec = (const float*)d_in[2];
  float* lat = (float*)d_out;                    // [NR][DH], also dense scratch
  float* recon = lat + (size_t)NR * DH;          // [NR][DIN]
  char* w = (char*)d_ws;
  __bf16* xh = (__bf16*)w;   w += (size_t)NR * DIN * 2;
  __bf16* xl = (__bf16*)w;   w += (size_t)NR * DIN * 2;
  __bf16* weh = (__bf16*)w;  w += (size_t)DH * DIN * 2;
  __bf16* wel = (__bf16*)w;  w += (size_t)DH * DIN * 2;
  float* wdecT = (float*)w;  w += (size_t)DH * DIN * 4;
  float* fvals = (float*)w;  w += (size_t)NR * KTOP * 4;
  int* fidx = (int*)w;       w += (size_t)NR * KTOP * 4;

  k_split<<<(NR * DIN / 4 + 255) / 256, 256, 0, stream>>>(x, xh, xl, NR * DIN / 4);
  k_split<<<(DH * DIN / 4 + 255) / 256, 256, 0, stream>>>(W_enc, weh, wel, DH * DIN / 4);
  k_transpose<<<dim3(DH / 32, DIN / 32), dim3(32, 8), 0, stream>>>(W_dec, wdecT);
  k_gemm<<<dim3(DH / 128, NR / 128), 256, 0, stream>>>(xh, xl, weh, wel, lat);
  k_topk<<<NR, 256, 0, stream>>>(lat, x, W_enc, fvals, fidx);
  k_decode<<<NR, 256, 0, stream>>>(fvals, fidx, wdecT, recon);
}

// Round 2
// 1545.657 us; speedup vs baseline: 1.4762x; 1.4762x over previous
//
#include <hip/hip_runtime.h>

#define NR 8192
#define DIN 768
#define DH 16384
#define KTOP 32
#define CAND 256

typedef __attribute__((ext_vector_type(8))) __bf16 bf16x8;
typedef __attribute__((ext_vector_type(4))) __bf16 bf16x4;
typedef __attribute__((ext_vector_type(4))) float f32x4;

__device__ __forceinline__ void gload16(const void* g, void* s) {
  __builtin_amdgcn_global_load_lds((const __attribute__((address_space(1))) void*)g,
                                   (__attribute__((address_space(3))) void*)s, 16, 0, 0);
}

// f32 -> (hi, lo) bf16 split, 4 elems/thread
__global__ __launch_bounds__(256) void k_split(const float* __restrict__ in,
    __bf16* __restrict__ hi, __bf16* __restrict__ lo, int n4) {
  int i = blockIdx.x * 256 + threadIdx.x;
  if (i >= n4) return;
  float4 v = ((const float4*)in)[i];
  bf16x4 h, l;
  float f;
  f = v.x; h[0] = (__bf16)f; l[0] = (__bf16)(f - (float)h[0]);
  f = v.y; h[1] = (__bf16)f; l[1] = (__bf16)(f - (float)h[1]);
  f = v.z; h[2] = (__bf16)f; l[2] = (__bf16)(f - (float)h[2]);
  f = v.w; h[3] = (__bf16)f; l[3] = (__bf16)(f - (float)h[3]);
  ((bf16x4*)hi)[i] = h;
  ((bf16x4*)lo)[i] = l;
}

// W_dec [768][16384] -> wdecT [16384][768]
__global__ __launch_bounds__(256) void k_transpose(const float* __restrict__ in,
                                                   float* __restrict__ outT) {
  __shared__ float tile[32][33];
  int tx = threadIdx.x, ty = threadIdx.y;
  int hb = blockIdx.x * 32, db = blockIdx.y * 32;
  for (int i = 0; i < 32; i += 8)
    tile[ty + i][tx] = in[(size_t)(db + ty + i) * DH + hb + tx];
  __syncthreads();
  for (int i = 0; i < 32; i += 8)
    outT[(size_t)(hb + ty + i) * DIN + db + tx] = tile[tx][ty + i];
}

// split-bf16 GEMM: out[NR][DH] = relu(x @ W_enc^T), 3-term hi/lo compensation
__global__ __launch_bounds__(256) void k_gemm(const __bf16* __restrict__ Ah,
    const __bf16* __restrict__ Al, const __bf16* __restrict__ Bh,
    const __bf16* __restrict__ Bl, float* __restrict__ out) {
  __shared__ __bf16 sAh[128 * 64], sAl[128 * 64], sBh[128 * 64], sBl[128 * 64];
  const int tid = threadIdx.x;
  const int l = tid & 63;
  const int w = tid >> 6;
  const int wm = w >> 1, wn = w & 1;
  const size_t row0 = (size_t)blockIdx.y * 128;
  const size_t col0 = (size_t)blockIdx.x * 128;
  f32x4 acc[4][4] = {};
  const int cr = l >> 3;         // row within 8-row chunk
  const int cc = (l & 7) * 8;    // k-element offset
  for (int t = 0; t < 12; ++t) {
    const int k0 = t * 64;
    for (int i = 0; i < 4; ++i) {
      const int c = i * 4 + w;       // chunk 0..15 (wave-uniform)
      const int r = c * 8 + cr;      // tile row 0..127
      const int ldso = c * 512;      // LDS element offset (1KB chunks)
      gload16(Ah + (row0 + r) * DIN + k0 + cc, sAh + ldso);
      gload16(Al + (row0 + r) * DIN + k0 + cc, sAl + ldso);
      gload16(Bh + (col0 + r) * DIN + k0 + cc, sBh + ldso);
      gload16(Bl + (col0 + r) * DIN + k0 + cc, sBl + ldso);
    }
    __syncthreads();
#pragma unroll
    for (int kk = 0; kk < 2; ++kk) {
      const int kb = kk * 32 + (l >> 4) * 8;
      bf16x8 ah[4], al[4], bh[4], bl[4];
#pragma unroll
      for (int mi = 0; mi < 4; ++mi) {
        int ro = (wm * 64 + mi * 16 + (l & 15)) * 64 + kb;
        ah[mi] = *(const bf16x8*)(sAh + ro);
        al[mi] = *(const bf16x8*)(sAl + ro);
      }
#pragma unroll
      for (int ni = 0; ni < 4; ++ni) {
        int ro = (wn * 64 + ni * 16 + (l & 15)) * 64 + kb;
        bh[ni] = *(const bf16x8*)(sBh + ro);
        bl[ni] = *(const bf16x8*)(sBl + ro);
      }
#pragma unroll
      for (int mi = 0; mi < 4; ++mi)
#pragma unroll
        for (int ni = 0; ni < 4; ++ni) {
          acc[mi][ni] = __builtin_amdgcn_mfma_f32_16x16x32_bf16(ah[mi], bh[ni], acc[mi][ni], 0, 0, 0);
          acc[mi][ni] = __builtin_amdgcn_mfma_f32_16x16x32_bf16(ah[mi], bl[ni], acc[mi][ni], 0, 0, 0);
          acc[mi][ni] = __builtin_amdgcn_mfma_f32_16x16x32_bf16(al[mi], bh[ni], acc[mi][ni], 0, 0, 0);
        }
    }
    __syncthreads();
  }
#pragma unroll
  for (int mi = 0; mi < 4; ++mi)
#pragma unroll
    for (int ni = 0; ni < 4; ++ni)
#pragma unroll
      for (int rg = 0; rg < 4; ++rg) {
        size_t rr = row0 + wm * 64 + mi * 16 + (l >> 4) * 4 + rg;
        size_t cg = col0 + wn * 64 + ni * 16 + (l & 15);
        float v = acc[mi][ni][rg];
        out[rr * DH + cg] = v > 0.f ? v : 0.f;
      }
}

// per-row exact top-32: register-resident row, max-anchored windowed radix
// select (no LDS staging, few atomics), O(C^2) rank sort, rare f64 tie
// refinement, in-place zero+scatter, emit (idx,val) lists.
__global__ __launch_bounds__(256) void k_topk(float* __restrict__ lat,
    const float* __restrict__ x, const float* __restrict__ W_enc,
    float* __restrict__ fvals, int* __restrict__ fidx) {
  const int r = blockIdx.x;
  const int tid = threadIdx.x;
  float* row = lat + (size_t)r * DH;

  __shared__ int hist[256];
  __shared__ int suf[256];
  __shared__ float cval[CAND];
  __shared__ int cidx[CAND];
  __shared__ float sv[CAND];
  __shared__ int sidx[CAND];
  __shared__ double dval[CAND];
  __shared__ float wmax[4];
  __shared__ unsigned s_uthr;
  __shared__ int s_cnt;

  // 64 values per thread, register-resident (all indices compile-time)
  float v[64];
  const float4* row4 = (const float4*)row;
#pragma unroll
  for (int j = 0; j < 16; ++j) {
    float4 q = row4[tid + j * 256];
    v[j * 4 + 0] = q.x; v[j * 4 + 1] = q.y;
    v[j * 4 + 2] = q.z; v[j * 4 + 3] = q.w;
  }

  // block max
  float m = 0.f;
#pragma unroll
  for (int j = 0; j < 64; ++j) m = fmaxf(m, v[j]);
#pragma unroll
  for (int off = 32; off; off >>= 1) m = fmaxf(m, __shfl_xor(m, off));
  if ((tid & 63) == 0) wmax[tid >> 6] = m;
  __syncthreads();
  const float M = fmaxf(fmaxf(wmax[0], wmax[1]), fmaxf(wmax[2], wmax[3]));

  const float4 z4 = {0.f, 0.f, 0.f, 0.f};
  if (M <= 0.f) {  // no positive activations: everything zero (uniform path)
#pragma unroll
    for (int j = 0; j < 16; ++j) ((float4*)row)[tid + j * 256] = z4;
    if (tid < KTOP) { fvals[r * KTOP + tid] = 0.f; fidx[r * KTOP + tid] = 0; }
    return;
  }

  // windowed radix select: 256 bins of 2^16 uint-keys within (base, uhi]
  unsigned uhi = __float_as_uint(M);
  const unsigned W = 1u << 24;
  unsigned base = 0;
  int above = 0;
  bool done = false;
  for (int iter = 0; iter < 80 && !done; ++iter) {
    base = uhi > W ? uhi - W : 0u;
    hist[tid] = 0;
    __syncthreads();
#pragma unroll
    for (int j = 0; j < 64; ++j) {
      unsigned u = __float_as_uint(v[j]);
      if (u > base && u <= uhi) atomicAdd(&hist[(u - 1 - base) >> 16], 1);
    }
    __syncthreads();
    { int s = 0; for (int j = tid; j < 256; ++j) s += hist[j]; suf[tid] = s; }
    __syncthreads();
    if (above + suf[0] >= KTOP || base == 0) {
      done = true;
    } else {
      above += suf[0];
      uhi = base;
      __syncthreads();
    }
  }
  if (tid == 0) {
    int t = 0;
    for (int b = 255; b >= 1; --b)
      if (above + suf[b] >= KTOP) { t = b; break; }
    unsigned raw = base + 1 + ((unsigned)t << 16);
    s_uthr = raw > (1u << 16) ? raw - (1u << 16) : 0u;  // one extra bin: tie guard
    s_cnt = 0;
  }
  __syncthreads();
  const unsigned uthr = s_uthr;

  // gather candidates
#pragma unroll
  for (int j = 0; j < 64; ++j) {
    unsigned u = __float_as_uint(v[j]);
    if (u && u >= uthr) {
      int p = atomicAdd(&s_cnt, 1);
      if (p < CAND) { cval[p] = v[j]; cidx[p] = (tid + (j >> 2) * 256) * 4 + (j & 3); }
    }
  }
  __syncthreads();
  const int C = min(s_cnt, CAND);

  // exact rank sort of candidates (desc)
  if (tid < C) {
    float vv = cval[tid];
    int rk = 0;
    for (int j = 0; j < C; ++j) {
      float vj = cval[j];
      rk += (vj > vv) || (vj == vv && j < tid);
    }
    sv[rk] = vv; sidx[rk] = cidx[tid];
  }
  __syncthreads();

  bool amb = (C > KTOP) && (sv[KTOP - 1] - sv[KTOP] < 1e-4f);
  if (amb) {
    // f64 recompute of all candidates: selection becomes f64-exact
    const int wl = tid & 63, wv = tid >> 6;
    const float* xr = x + (size_t)r * DIN;
    for (int c = wv; c < C; c += 4) {
      const float* wrow = W_enc + (size_t)cidx[c] * DIN;
      double s = 0.0;
      for (int k = wl; k < DIN; k += 64)
        s += (double)xr[k] * (double)wrow[k];
#pragma unroll
      for (int off = 32; off; off >>= 1) s += __shfl_down(s, off);
      if (wl == 0) dval[c] = s > 0.0 ? s : 0.0;
    }
    __syncthreads();
    if (tid < C) {
      double vv = dval[tid];
      int rk = 0;
      for (int j = 0; j < C; ++j) {
        double vj = dval[j];
        rk += (vj > vv) || (vj == vv && j < tid);
      }
      sv[rk] = (float)vv; sidx[rk] = cidx[tid];
    }
    __syncthreads();
  }

  // zero the row, then scatter the kept entries
#pragma unroll
  for (int j = 0; j < 16; ++j) ((float4*)row)[tid + j * 256] = z4;
  __syncthreads();
  if (tid < KTOP) {
    float ov = (tid < C) ? sv[tid] : 0.f;
    int oi = (tid < C) ? sidx[tid] : 0;
    if (tid < C) row[oi] = ov;
    fvals[r * KTOP + tid] = ov;
    fidx[r * KTOP + tid] = oi;
  }
}

// recon[r][:] = sum_j val_j * wdecT[idx_j][:]
__global__ __launch_bounds__(256) void k_decode(const float* __restrict__ fvals,
    const int* __restrict__ fidx, const float* __restrict__ wdecT,
    float* __restrict__ recon) {
  const int r = blockIdx.x, tid = threadIdx.x;
  __shared__ float lv[KTOP];
  __shared__ int li[KTOP];
  if (tid < KTOP) { lv[tid] = fvals[r * KTOP + tid]; li[tid] = fidx[r * KTOP + tid]; }
  __syncthreads();
  float a0 = 0.f, a1 = 0.f, a2 = 0.f;
#pragma unroll
  for (int j = 0; j < KTOP; ++j) {
    const float* wrow = wdecT + (size_t)li[j] * DIN;
    float v = lv[j];
    a0 += v * wrow[tid];
    a1 += v * wrow[tid + 256];
    a2 += v * wrow[tid + 512];
  }
  float* o = recon + (size_t)r * DIN;
  o[tid] = a0;
  o[tid + 256] = a1;
  o[tid + 512] = a2;
}

extern "C" void kernel_launch(void* const* d_in, const int* in_sizes, int n_in,
                              void* d_out, int out_size, void* d_ws, size_t ws_size,
                              hipStream_t stream) {
  const float* x = (const float*)d_in[0];
  const float* W_enc = (const float*)d_in[1];
  const float* W_dec = (const float*)d_in[2];
  float* lat = (float*)d_out;                    // [NR][DH], also dense scratch
  float* recon = lat + (size_t)NR * DH;          // [NR][DIN]
  char* w = (char*)d_ws;
  __bf16* xh = (__bf16*)w;   w += (size_t)NR * DIN * 2;
  __bf16* xl = (__bf16*)w;   w += (size_t)NR * DIN * 2;
  __bf16* weh = (__bf16*)w;  w += (size_t)DH * DIN * 2;
  __bf16* wel = (__bf16*)w;  w += (size_t)DH * DIN * 2;
  float* wdecT = (float*)w;  w += (size_t)DH * DIN * 4;
  float* fvals = (float*)w;  w += (size_t)NR * KTOP * 4;
  int* fidx = (int*)w;       w += (size_t)NR * KTOP * 4;

  k_split<<<(NR * DIN / 4 + 255) / 256, 256, 0, stream>>>(x, xh, xl, NR * DIN / 4);
  k_split<<<(DH * DIN / 4 + 255) / 256, 256, 0, stream>>>(W_enc, weh, wel, DH * DIN / 4);
  k_transpose<<<dim3(DH / 32, DIN / 32), dim3(32, 8), 0, stream>>>(W_dec, wdecT);
  k_gemm<<<dim3(DH / 128, NR / 128), 256, 0, stream>>>(xh, xl, weh, wel, lat);
  k_topk<<<NR, 256, 0, stream>>>(lat, x, W_enc, fvals, fidx);
  k_decode<<<NR, 256, 0, stream>>>(fvals, fidx, wdecT, recon);
}

// Round 7
// 1273.396 us; speedup vs baseline: 1.7918x; 1.2138x over previous
//
#include <hip/hip_runtime.h>

#define NR 8192
#define DIN 768
#define DH 16384
#define KTOP 32
#define CAND 256

typedef __attribute__((ext_vector_type(8))) __bf16 bf16x8;
typedef __attribute__((ext_vector_type(4))) float f32x4;

__device__ __forceinline__ unsigned short f2bf(float f) {
  unsigned u = __float_as_uint(f);
  return (unsigned short)((u + 0x7fffu + ((u >> 16) & 1u)) >> 16);
}
__device__ __forceinline__ float bf2f(unsigned short h) {
  return __uint_as_float((unsigned)h << 16);
}

__device__ __forceinline__ void gload16(const void* g, void* s) {
  __builtin_amdgcn_global_load_lds((const __attribute__((address_space(1))) void*)g,
                                   (__attribute__((address_space(3))) void*)s, 16, 0, 0);
}

// f32 -> bf16 cast, 4 elems/thread
__global__ __launch_bounds__(256) void k_cast(const float* __restrict__ in,
    unsigned short* __restrict__ out, int n4) {
  int i = blockIdx.x * 256 + threadIdx.x;
  if (i >= n4) return;
  float4 v = ((const float4*)in)[i];
  ushort4 o;
  o.x = f2bf(v.x); o.y = f2bf(v.y); o.z = f2bf(v.z); o.w = f2bf(v.w);
  ((ushort4*)out)[i] = o;
}

// W_dec [768][16384] f32 -> wdecT [16384][768] bf16
__global__ __launch_bounds__(256) void k_transpose(const float* __restrict__ in,
                                                   unsigned short* __restrict__ outT) {
  __shared__ float tile[32][33];
  int tx = threadIdx.x, ty = threadIdx.y;
  int hb = blockIdx.x * 32, db = blockIdx.y * 32;
  for (int i = 0; i < 32; i += 8)
    tile[ty + i][tx] = in[(size_t)(db + ty + i) * DH + hb + tx];
  __syncthreads();
  for (int i = 0; i < 32; i += 8)
    outT[(size_t)(hb + ty + i) * DIN + db + tx] = f2bf(tile[tx][ty + i]);
}

// single-term bf16 GEMM: out[NR][DH] = relu(x @ W_enc^T), f32 out
__global__ __launch_bounds__(256) void k_gemm(const __bf16* __restrict__ Ah,
    const __bf16* __restrict__ Bh, float* __restrict__ out) {
  __shared__ __bf16 sAh[128 * 64], sBh[128 * 64];
  const int tid = threadIdx.x;
  const int l = tid & 63;
  const int w = tid >> 6;
  const int wm = w >> 1, wn = w & 1;
  // bijective XCD swizzle (8192 % 8 == 0): XCD x gets a contiguous chunk
  const int bid = blockIdx.x;
  const int sw = (bid & 7) * 1024 + (bid >> 3);
  const size_t row0 = (size_t)(sw >> 7) * 128;   // 64 row-tiles
  const size_t col0 = (size_t)(sw & 127) * 128;  // 128 col-tiles
  f32x4 acc[4][4] = {};
  const int cr = l >> 3;
  const int cc = (l & 7) * 8;
  for (int t = 0; t < 12; ++t) {
    const int k0 = t * 64;
    for (int i = 0; i < 4; ++i) {
      const int c = i * 4 + w;
      const int r = c * 8 + cr;
      const int ldso = c * 512;
      gload16(Ah + (row0 + r) * DIN + k0 + cc, sAh + ldso);
      gload16(Bh + (col0 + r) * DIN + k0 + cc, sBh + ldso);
    }
    __syncthreads();
#pragma unroll
    for (int kk = 0; kk < 2; ++kk) {
      const int kb = kk * 32 + (l >> 4) * 8;
      bf16x8 ah[4], bh[4];
#pragma unroll
      for (int mi = 0; mi < 4; ++mi)
        ah[mi] = *(const bf16x8*)(sAh + (wm * 64 + mi * 16 + (l & 15)) * 64 + kb);
#pragma unroll
      for (int ni = 0; ni < 4; ++ni)
        bh[ni] = *(const bf16x8*)(sBh + (wn * 64 + ni * 16 + (l & 15)) * 64 + kb);
#pragma unroll
      for (int mi = 0; mi < 4; ++mi)
#pragma unroll
        for (int ni = 0; ni < 4; ++ni)
          acc[mi][ni] = __builtin_amdgcn_mfma_f32_16x16x32_bf16(ah[mi], bh[ni], acc[mi][ni], 0, 0, 0);
    }
    __syncthreads();
  }
#pragma unroll
  for (int mi = 0; mi < 4; ++mi)
#pragma unroll
    for (int ni = 0; ni < 4; ++ni)
#pragma unroll
      for (int rg = 0; rg < 4; ++rg) {
        size_t rr = row0 + wm * 64 + mi * 16 + (l >> 4) * 4 + rg;
        size_t cg = col0 + wn * 64 + ni * 16 + (l & 15);
        float v = acc[mi][ni][rg];
        out[rr * DH + cg] = v > 0.f ? v : 0.f;
      }
}

// per-row top-32: register-resident row, windowed radix cutoff (+2-bin margin),
// ALWAYS f64-exact recompute of all candidates, rank, zero+scatter.
__global__ __launch_bounds__(256) void k_topk(float* __restrict__ lat,
    const float* __restrict__ x, const float* __restrict__ W_enc,
    float* __restrict__ fvals, int* __restrict__ fidx) {
  const int r = blockIdx.x;
  const int tid = threadIdx.x;
  float* row = lat + (size_t)r * DH;

  __shared__ int hist[256];
  __shared__ int suf[256];
  __shared__ int cidx[CAND];
  __shared__ double dval[CAND];
  __shared__ float sval[KTOP];
  __shared__ int sidx[KTOP];
  __shared__ float xs[DIN];
  __shared__ float wmax[4];
  __shared__ unsigned s_uthr;
  __shared__ int s_cnt;

  // 64 values per thread, register-resident
  float v[64];
  const float4* row4 = (const float4*)row;
#pragma unroll
  for (int j = 0; j < 16; ++j) {
    float4 q = row4[tid + j * 256];
    v[j * 4 + 0] = q.x; v[j * 4 + 1] = q.y;
    v[j * 4 + 2] = q.z; v[j * 4 + 3] = q.w;
  }
  // stage x row for the exact recompute
  if (tid < DIN / 4) ((float4*)xs)[tid] = ((const float4*)(x + (size_t)r * DIN))[tid];
  if (tid < KTOP) { sval[tid] = 0.f; sidx[tid] = 0; }

  // block max
  float m = 0.f;
#pragma unroll
  for (int j = 0; j < 64; ++j) m = fmaxf(m, v[j]);
#pragma unroll
  for (int off = 32; off; off >>= 1) m = fmaxf(m, __shfl_xor(m, off));
  if ((tid & 63) == 0) wmax[tid >> 6] = m;
  __syncthreads();
  const float M = fmaxf(fmaxf(wmax[0], wmax[1]), fmaxf(wmax[2], wmax[3]));

  int C = 0;
  if (M > 0.f) {
    // windowed radix select: 256 bins of 2^16 uint-keys within (base, uhi]
    unsigned uhi = __float_as_uint(M);
    const unsigned W = 1u << 24;
    unsigned base = 0;
    int above = 0;
    bool done = false;
    for (int iter = 0; iter < 80 && !done; ++iter) {
      base = uhi > W ? uhi - W : 0u;
      hist[tid] = 0;
      __syncthreads();
#pragma unroll
      for (int j = 0; j < 64; ++j) {
        unsigned u = __float_as_uint(v[j]);
        if (u > base && u <= uhi) atomicAdd(&hist[(u - 1 - base) >> 16], 1);
      }
      __syncthreads();
      { int s = 0; for (int j = tid; j < 256; ++j) s += hist[j]; suf[tid] = s; }
      __syncthreads();
      if (above + suf[0] >= KTOP || base == 0) {
        done = true;
      } else {
        above += suf[0];
        uhi = base;
        __syncthreads();
      }
    }
    if (tid == 0) {
      int t = 0;
      for (int b = 255; b >= 1; --b)
        if (above + suf[b] >= KTOP) { t = b; break; }
      unsigned raw = base + 1 + ((unsigned)t << 16);
      // 2-bin margin (>= ~0.03 abs at cutoff ~ 20 sigma of 1-term bf16 GEMM err)
      s_uthr = raw > (2u << 16) ? raw - (2u << 16) : 1u;
      s_cnt = 0;
    }
    __syncthreads();
    const unsigned uthr = s_uthr;
    // gather candidate indices
#pragma unroll
    for (int j = 0; j < 64; ++j) {
      unsigned u = __float_as_uint(v[j]);
      if (u && u >= uthr) {
        int p = atomicAdd(&s_cnt, 1);
        if (p < CAND) cidx[p] = (tid + (j >> 2) * 256) * 4 + (j & 3);
      }
    }
    __syncthreads();
    C = min(s_cnt, CAND);

    // f64-exact recompute of ALL candidates
    const int wl = tid & 63, wv = tid >> 6;
    for (int c = wv; c < C; c += 4) {
      const float* wrow = W_enc + (size_t)cidx[c] * DIN;
      double s = 0.0;
#pragma unroll
      for (int k = 0; k < DIN / 64; ++k)
        s += (double)xs[wl + k * 64] * (double)wrow[wl + k * 64];
#pragma unroll
      for (int off = 32; off; off >>= 1) s += __shfl_down(s, off);
      if (wl == 0) dval[c] = s;
    }
    __syncthreads();

    // exact rank (desc, tie -> lower original index)
    if (tid < C) {
      double vv = dval[tid];
      int ii = cidx[tid];
      int rk = 0;
      for (int j = 0; j < C; ++j) {
        double vj = dval[j];
        rk += (vj > vv) || (vj == vv && cidx[j] < ii);
      }
      if (rk < KTOP) { sval[rk] = (float)vv; sidx[rk] = ii; }
    }
    __syncthreads();
  }

  // zero the row, scatter kept entries, emit lists
  const float4 z4 = {0.f, 0.f, 0.f, 0.f};
#pragma unroll
  for (int j = 0; j < 16; ++j) ((float4*)row)[tid + j * 256] = z4;
  __syncthreads();
  if (tid < KTOP) {
    float ov = sval[tid];
    int oi = sidx[tid];
    if (ov > 0.f) row[oi] = ov;
    fvals[r * KTOP + tid] = ov;
    fidx[r * KTOP + tid] = oi;
  }
}

// recon[r][:] = sum_j val_j * wdecT[idx_j][:]  (bf16 decoder table)
// 256 threads x 3 elements = 768 = DIN. Table is L2/L3-resident.
__global__ __launch_bounds__(256) void k_decode(const float* __restrict__ fvals,
    const int* __restrict__ fidx, const unsigned short* __restrict__ wdecT,
    float* __restrict__ recon) {
  const int r = blockIdx.x, tid = threadIdx.x;
  __shared__ float lv[KTOP];
  __shared__ int li[KTOP];
  if (tid < KTOP) { lv[tid] = fvals[r * KTOP + tid]; li[tid] = fidx[r * KTOP + tid]; }
  __syncthreads();
  float a0 = 0.f, a1 = 0.f, a2 = 0.f;
  for (int j = 0; j < KTOP; ++j) {
    float v = lv[j];
    if (v == 0.f) break;  // sorted desc: rest are zero
    const unsigned short* wr = wdecT + (size_t)li[j] * DIN;
    a0 += v * bf2f(wr[tid]);
    a1 += v * bf2f(wr[tid + 256]);
    a2 += v * bf2f(wr[tid + 512]);
  }
  float* o = recon + (size_t)r * DIN;
  o[tid] = a0;
  o[tid + 256] = a1;
  o[tid + 512] = a2;
}

extern "C" void kernel_launch(void* const* d_in, const int* in_sizes, int n_in,
                              void* d_out, int out_size, void* d_ws, size_t ws_size,
                              hipStream_t stream) {
  const float* x = (const float*)d_in[0];
  const float* W_enc = (const float*)d_in[1];
  const float* W_dec = (const float*)d_in[2];
  float* lat = (float*)d_out;                    // [NR][DH], also dense scratch
  float* recon = lat + (size_t)NR * DH;          // [NR][DIN]
  char* w = (char*)d_ws;
  unsigned short* xh = (unsigned short*)w;   w += (size_t)NR * DIN * 2;
  unsigned short* weh = (unsigned short*)w;  w += (size_t)DH * DIN * 2;
  unsigned short* wdecT = (unsigned short*)w; w += (size_t)DH * DIN * 2;
  float* fvals = (float*)w;  w += (size_t)NR * KTOP * 4;
  int* fidx = (int*)w;       w += (size_t)NR * KTOP * 4;

  k_cast<<<(NR * DIN / 4 + 255) / 256, 256, 0, stream>>>(x, xh, NR * DIN / 4);
  k_cast<<<(DH * DIN / 4 + 255) / 256, 256, 0, stream>>>(W_enc, weh, DH * DIN / 4);
  k_transpose<<<dim3(DH / 32, DIN / 32), dim3(32, 8), 0, stream>>>(W_dec, wdecT);
  k_gemm<<<NR / 128 * (DH / 128), 256, 0, stream>>>((const __bf16*)xh, (const __bf16*)weh, lat);
  k_topk<<<NR, 256, 0, stream>>>(lat, x, W_enc, fvals, fidx);
  k_decode<<<NR, 256, 0, stream>>>(fvals, fidx, wdecT, recon);
}